// Round 2
// 1175.130 us; speedup vs baseline: 1.1539x; 1.1539x over previous
//
#include <hip/hip_runtime.h>
#include <cstddef>

#define NN 50000
#define NE 800000

typedef __bf16 bf16x8 __attribute__((ext_vector_type(8)));
typedef float floatx4 __attribute__((ext_vector_type(4)));

__device__ __forceinline__ float bflo2f(unsigned int u) {
    union { unsigned int u; float f; } v; v.u = u << 16; return v.f;
}
__device__ __forceinline__ float bfhi2f(unsigned int u) {
    union { unsigned int u; float f; } v; v.u = u & 0xffff0000u; return v.f;
}
__device__ __forceinline__ unsigned short f2bf(float f) {
    union { float f; unsigned int u; } v; v.f = f;
    unsigned int u = v.u;
    unsigned int r = u + 0x7fffu + ((u >> 16) & 1u);   // RNE
    return (unsigned short)(r >> 16);
}

// ---------------- CSR build ----------------

__global__ void k_count(const int* __restrict__ e0, const int* __restrict__ e1,
                        const int* __restrict__ e2, const int* __restrict__ e3,
                        int* __restrict__ counts) {
    const int* es[4] = {e0, e1, e2, e3};
    int r = blockIdx.y;
    int i = blockIdx.x * blockDim.x + threadIdx.x;
    if (i < NE) {
        int d = es[r][NE + i];
        atomicAdd(&counts[r * NN + d], 1);
    }
}

__global__ void k_deg(const int* __restrict__ counts, float* __restrict__ dinv, int total) {
    int i = blockIdx.x * blockDim.x + threadIdx.x;
    if (i < total) {
        float d = (float)(counts[i] + 1);   // in-deg + self loop
        dinv[i] = rsqrtf(d);
    }
}

#define SCH 256
__global__ void k_scan_a(const int* __restrict__ counts, int* __restrict__ bsum, int n) {
    __shared__ int sd[SCH];
    int r = blockIdx.y, b = blockIdx.x, t = threadIdx.x;
    int i = b * SCH + t;
    int v = (i < n) ? counts[r * n + i] : 0;
    sd[t] = v; __syncthreads();
    for (int o = 1; o < SCH; o <<= 1) {
        int x = (t >= o) ? sd[t - o] : 0; __syncthreads();
        sd[t] += x; __syncthreads();
    }
    if (t == SCH - 1) bsum[r * gridDim.x + b] = sd[t];
}
__global__ void k_scan_b(int* __restrict__ bsum, int nch) {
    __shared__ int sd[SCH];
    int r = blockIdx.y, t = threadIdx.x;
    int v = (t < nch) ? bsum[r * nch + t] : 0;
    sd[t] = v; __syncthreads();
    for (int o = 1; o < SCH; o <<= 1) {
        int x = (t >= o) ? sd[t - o] : 0; __syncthreads();
        sd[t] += x; __syncthreads();
    }
    if (t < nch) bsum[r * nch + t] = sd[t] - v;   // exclusive
}
__global__ void k_scan_c(const int* __restrict__ counts, const int* __restrict__ bsum,
                         int* __restrict__ rowptr, int n, int nch) {
    __shared__ int sd[SCH];
    int r = blockIdx.y, b = blockIdx.x, t = threadIdx.x;
    int i = b * SCH + t;
    int v = (i < n) ? counts[r * n + i] : 0;
    sd[t] = v; __syncthreads();
    for (int o = 1; o < SCH; o <<= 1) {
        int x = (t >= o) ? sd[t - o] : 0; __syncthreads();
        sd[t] += x; __syncthreads();
    }
    if (i < n) {
        int off = bsum[r * nch + b] + sd[t] - v;
        rowptr[r * (n + 1) + i] = off;
    }
    if (b == 0 && t == 0) rowptr[r * (n + 1) + n] = NE;
}

// ---------------- bucketed CSR fill ----------------
// Replaces the old single-pass random-scatter k_fill (213 MB HBM writes from
// 4B scattered stores). Two passes with line-coalesced writes only.

#define NBUK 98          // dst >> 9  (512 nodes per bucket, 49999>>9 = 97)
#define BSH  9
#define ACH  4096        // edges per block in pass A
#define BCAP 12288       // LDS CSR-image capacity per bucket (mean 8192, +45 sigma)

// bfill[r*128+b] = rowptr[r][b<<9]  (bucket pair-segment base == CSR segment base)
__global__ void k_binit(const int* __restrict__ rowptr, int* __restrict__ bfill) {
    int i = blockIdx.x * blockDim.x + threadIdx.x;
    if (i < 4 * 128) {
        int r = i >> 7, b = i & 127;
        int node = b << BSH; if (node > NN) node = NN;
        bfill[i] = rowptr[r * (NN + 1) + node];
    }
}

// Pass A: per-block LDS binning of a 4096-edge chunk, then per-bucket bulk
// reservation (one global atomic per block-bucket) and contiguous flush of
// (src,dst) pairs into the bucket's pair segment.
__global__ __launch_bounds__(256) void k_bucketA(
        const int* __restrict__ e0, const int* __restrict__ e1,
        const int* __restrict__ e2, const int* __restrict__ e3,
        int* __restrict__ bfill, uint2* __restrict__ pairbuf) {
    __shared__ int lcnt[128];
    __shared__ int s1[128];
    __shared__ int lbase[128];
    __shared__ int lfil[128];
    __shared__ int gbase[128];
    __shared__ uint2 sbuf[ACH];

    const int* es[4] = {e0, e1, e2, e3};
    const int r = blockIdx.y;
    const int tid = threadIdx.x;
    const int* src = es[r];
    const int* dst = es[r] + NE;
    const int lo = blockIdx.x * ACH;
    int hi = lo + ACH; if (hi > NE) hi = NE;
    const int cnt = hi - lo;

    if (tid < 128) lcnt[tid] = 0;
    __syncthreads();

    // histogram
    for (int i = lo + tid; i < hi; i += 256)
        atomicAdd(&lcnt[dst[i] >> BSH], 1);
    __syncthreads();

    // exclusive scan over 128 buckets (Hillis-Steele)
    if (tid < 128) s1[tid] = lcnt[tid];
    __syncthreads();
    for (int o = 1; o < 128; o <<= 1) {
        int x = (tid < 128 && tid >= o) ? s1[tid - o] : 0;
        __syncthreads();
        if (tid < 128) s1[tid] += x;
        __syncthreads();
    }
    if (tid < 128) {
        int eb = s1[tid] - lcnt[tid];
        lbase[tid] = eb;
        lfil[tid] = eb;
    }
    __syncthreads();

    // place pairs bucket-ordered in LDS
    for (int i = lo + tid; i < hi; i += 256) {
        int d = dst[i];
        int b = d >> BSH;
        int p = atomicAdd(&lfil[b], 1);
        uint2 v; v.x = (unsigned int)src[i]; v.y = (unsigned int)d;
        sbuf[p] = v;
    }
    __syncthreads();

    // reserve global space: one atomic per non-empty bucket
    if (tid < 128 && lcnt[tid] > 0)
        gbase[tid] = atomicAdd(&bfill[r * 128 + tid], lcnt[tid]);
    __syncthreads();

    // flush: contiguous runs per bucket (binary search slot -> bucket)
    // NOTE: per-relation base (r*NE) — omitting it was the round-1 crash
    // (all relations raced into relation 0's region; pass B then indexed
    // its LDS cursor array with out-of-bucket dst values).
    uint2* pout = pairbuf + (size_t)r * NE;
    for (int i = tid; i < cnt; i += 256) {
        int loB = 0, hiB = 128;
        while (hiB - loB > 1) {
            int m = (loB + hiB) >> 1;
            if (lbase[m] <= i) loB = m; else hiB = m;
        }
        pout[(size_t)gbase[loB] + (i - lbase[loB])] = sbuf[i];
    }
}

// Pass B: one block per bucket. Read pair segment coalesced, scatter src into
// an LDS image of the bucket's CSR segment (LDS atomics on per-row cursors),
// write the segment out fully coalesced. Zero global atomics.
__global__ __launch_bounds__(256) void k_bucketB(
        const uint2* __restrict__ pairbuf, const int* __restrict__ rowptr,
        int* __restrict__ csr_src) {
    __shared__ int csrimg[BCAP];
    __shared__ int lfil[512];

    const int r = blockIdx.y;
    const int b = blockIdx.x;
    const int tid = threadIdx.x;
    const int node_lo = b << BSH;
    int node_hi = node_lo + 512; if (node_hi > NN) node_hi = NN;
    const int* rp = rowptr + r * (NN + 1);
    const int seg0 = rp[node_lo];
    const int seg1 = rp[node_hi];
    const int nr = node_hi - node_lo;

    for (int j = tid; j < nr; j += 256) lfil[j] = rp[node_lo + j] - seg0;
    __syncthreads();

    const uint2* pb = pairbuf + (size_t)r * NE;
    for (int i = seg0 + tid; i < seg1; i += 256) {
        uint2 p = pb[i];
        int li = (int)p.y - node_lo;
        if (li >= 0 && li < 512) {           // defensive: degrade to wrong-answer, never LDS-OOB
            int s = atomicAdd(&lfil[li], 1);
            if (s >= 0 && s < BCAP) csrimg[s] = (int)p.x;
        }
    }
    __syncthreads();

    int* co = csr_src + (size_t)r * NE + seg0;
    const int n = seg1 - seg0;
    for (int k = tid; k < n; k += 256) co[k] = csrimg[k];
}

// ---------------- batched weight transpose: W[KxM] fp32 -> Wt[MxK] bf16 ----------------

struct WTArgs {
    const float* W[10];
    unsigned short* Wt[10];
    int M[10];   // K is always 256
};

__global__ void k_wT_all(WTArgs a) {
    int g = blockIdx.y;
    int M = a.M[g];
    int total = 256 * M;
    int i = blockIdx.x * blockDim.x + threadIdx.x;
    if (i < total) {
        int m = i >> 8, k = i & 255;        // i = m*256 + k (Wt layout [M x 256])
        a.Wt[g][i] = f2bf(a.W[g][(size_t)k * M + m]);
    }
}

// ---------------- MFMA GEMM ----------------
// C[nrows x ncols] = A[nrows x K] * Bt[ncols x K]^T
// AF32: A is fp32 (converted to bf16 while staging); else A is bf16.
// mode 0: store bf16 to outBf
// mode 1: outF = acc + bias[col] + 0.5*(add0+add1)   (fused residual combine)
#define GB_BM 128
#define GB_BN 128
#define GB_BK 32

template <bool AF32>
__global__ __launch_bounds__(256) void k_gemm(
        const void* __restrict__ Aptr, const unsigned short* __restrict__ Bt,
        int nrows, int K, int ncols,
        unsigned short* __restrict__ outBf, float* __restrict__ outF,
        const float* __restrict__ add0, const float* __restrict__ add1,
        const float* __restrict__ bias, int mode) {
    __shared__ __align__(16) unsigned short As[GB_BM][GB_BK];
    __shared__ __align__(16) unsigned short Bs[GB_BN][GB_BK];
    const int tid = threadIdx.x;
    const int lane = tid & 63;
    const int wid = tid >> 6;
    const int wm = (wid >> 1) * 64;
    const int wn = (wid & 1) * 64;
    const int row0 = blockIdx.x * GB_BM;
    const int col0 = blockIdx.y * GB_BN;
    const int lrow = lane & 15;
    const int lquad = lane >> 4;

    floatx4 acc[4][4];
#pragma unroll
    for (int i = 0; i < 4; i++)
#pragma unroll
        for (int j = 0; j < 4; j++) acc[i][j] = (floatx4){0.f, 0.f, 0.f, 0.f};

    for (int k0 = 0; k0 < K; k0 += GB_BK) {
#pragma unroll
        for (int t = 0; t < 2; t++) {
            int c = tid + t * 256;
            int r = c >> 2;
            int co = (c & 3) * 8;
            int gr = row0 + r; if (gr >= nrows) gr = nrows - 1;
            if constexpr (AF32) {
                const float* pa = (const float*)Aptr + (size_t)gr * K + k0 + co;
                float4 v0 = *(const float4*)pa;
                float4 v1 = *(const float4*)(pa + 4);
                uint4 o;
                o.x = (unsigned int)f2bf(v0.x) | ((unsigned int)f2bf(v0.y) << 16);
                o.y = (unsigned int)f2bf(v0.z) | ((unsigned int)f2bf(v0.w) << 16);
                o.z = (unsigned int)f2bf(v1.x) | ((unsigned int)f2bf(v1.y) << 16);
                o.w = (unsigned int)f2bf(v1.z) | ((unsigned int)f2bf(v1.w) << 16);
                *(uint4*)&As[r][co] = o;
            } else {
                *(uint4*)&As[r][co] =
                    *(const uint4*)((const unsigned short*)Aptr + (size_t)gr * K + k0 + co);
            }
            int gc = col0 + r;   // ncols multiple of 128 -> always valid
            *(uint4*)&Bs[r][co] = *(const uint4*)(Bt + (size_t)gc * K + k0 + co);
        }
        __syncthreads();
        bf16x8 af[4], bfr[4];
#pragma unroll
        for (int i = 0; i < 4; i++) af[i] = *(const bf16x8*)&As[wm + 16 * i + lrow][lquad * 8];
#pragma unroll
        for (int j = 0; j < 4; j++) bfr[j] = *(const bf16x8*)&Bs[wn + 16 * j + lrow][lquad * 8];
#pragma unroll
        for (int i = 0; i < 4; i++)
#pragma unroll
            for (int j = 0; j < 4; j++)
                acc[i][j] = __builtin_amdgcn_mfma_f32_16x16x32_bf16(af[i], bfr[j], acc[i][j], 0, 0, 0);
        __syncthreads();
    }

#pragma unroll
    for (int i = 0; i < 4; i++) {
#pragma unroll
        for (int j = 0; j < 4; j++) {
            int col = col0 + wn + 16 * j + lrow;
#pragma unroll
            for (int r = 0; r < 4; r++) {
                int row = row0 + wm + 16 * i + lquad * 4 + r;
                if (row < nrows) {
                    float v = acc[i][j][r];
                    size_t idx = (size_t)row * ncols + col;
                    if (mode == 0) {
                        outBf[idx] = f2bf(v);
                    } else {
                        outF[idx] = v + bias[col] + 0.5f * (add0[idx] + add1[idx]);
                    }
                }
            }
        }
    }
}

// ---------------- GCN aggregate (CSR gather) ----------------
// out = lrelu( di*( sum_e dinv[s]*xw[s] + di*xw[i] ) + bias ),  di = dinv[i]
// mode 0 -> bf16 outB ; mode 1 -> fp32 outF

__device__ __forceinline__ void ldrow4(const unsigned short* p, float* o) {
    uint2 r = *(const uint2*)p;
    o[0] = bflo2f(r.x & 0xffffu); o[1] = bfhi2f(r.x);
    o[2] = bflo2f(r.y & 0xffffu); o[3] = bfhi2f(r.y);
}
__device__ __forceinline__ void ldrow2(const unsigned short* p, float* o) {
    unsigned int r = *(const unsigned int*)p;
    o[0] = bflo2f(r & 0xffffu); o[1] = bfhi2f(r);
}

template <int NC>
__global__ __launch_bounds__(256) void k_aggregate(
        const unsigned short* __restrict__ xw,
        const int* __restrict__ rowptr,
        const int* __restrict__ cs,
        const float* __restrict__ dinv,
        const float* __restrict__ bias,
        unsigned short* __restrict__ outB,
        float* __restrict__ outF, int mode, int n) {
    constexpr int F = NC * 64;
    const int lane = threadIdx.x & 63;
    const int wid = blockIdx.x * (blockDim.x >> 6) + (threadIdx.x >> 6);
    const int nw = gridDim.x * (blockDim.x >> 6);
    const int fb = lane * NC;

    float bv[NC];
#pragma unroll
    for (int c = 0; c < NC; c++) bv[c] = bias[fb + c];

    for (int i = wid; i < n; i += nw) {
        float di = dinv[i];
        float acc[NC];
        {
            float rv[NC];
            if constexpr (NC == 4) ldrow4(xw + (size_t)i * F + fb, rv);
            else                   ldrow2(xw + (size_t)i * F + fb, rv);
#pragma unroll
            for (int c = 0; c < NC; c++) acc[c] = di * rv[c];
        }
        int e0 = rowptr[i], e1 = rowptr[i + 1];
        int j = e0;
        for (; j + 3 < e1; j += 4) {
            int s0 = cs[j], s1 = cs[j + 1], s2 = cs[j + 2], s3 = cs[j + 3];
            float c0 = dinv[s0], c1 = dinv[s1], c2 = dinv[s2], c3 = dinv[s3];
            float r0[NC], r1[NC], r2[NC], r3[NC];
            if constexpr (NC == 4) {
                ldrow4(xw + (size_t)s0 * F + fb, r0);
                ldrow4(xw + (size_t)s1 * F + fb, r1);
                ldrow4(xw + (size_t)s2 * F + fb, r2);
                ldrow4(xw + (size_t)s3 * F + fb, r3);
            } else {
                ldrow2(xw + (size_t)s0 * F + fb, r0);
                ldrow2(xw + (size_t)s1 * F + fb, r1);
                ldrow2(xw + (size_t)s2 * F + fb, r2);
                ldrow2(xw + (size_t)s3 * F + fb, r3);
            }
#pragma unroll
            for (int c = 0; c < NC; c++)
                acc[c] += c0 * r0[c] + c1 * r1[c] + c2 * r2[c] + c3 * r3[c];
        }
        for (; j < e1; j++) {
            int s = cs[j];
            float cf = dinv[s];
            float rv[NC];
            if constexpr (NC == 4) ldrow4(xw + (size_t)s * F + fb, rv);
            else                   ldrow2(xw + (size_t)s * F + fb, rv);
#pragma unroll
            for (int c = 0; c < NC; c++) acc[c] += cf * rv[c];
        }
#pragma unroll
        for (int c = 0; c < NC; c++) {
            float v = di * acc[c] + bv[c];
            acc[c] = v >= 0.f ? v : 0.2f * v;
        }
        if (mode == 0) {
            if constexpr (NC == 4) {
                uint2 o;
                o.x = (unsigned int)f2bf(acc[0]) | ((unsigned int)f2bf(acc[1]) << 16);
                o.y = (unsigned int)f2bf(acc[2]) | ((unsigned int)f2bf(acc[3]) << 16);
                *(uint2*)(outB + (size_t)i * F + fb) = o;
            } else {
                *(unsigned int*)(outB + (size_t)i * F + fb) =
                    (unsigned int)f2bf(acc[0]) | ((unsigned int)f2bf(acc[1]) << 16);
            }
        } else {
            if constexpr (NC == 4) {
                float4 o = {acc[0], acc[1], acc[2], acc[3]};
                *(float4*)(outF + (size_t)i * F + fb) = o;
            } else {
                float2 o = {acc[0], acc[1]};
                *(float2*)(outF + (size_t)i * F + fb) = o;
            }
        }
    }
}

// ---------------- host launch ----------------

static inline size_t alignup(size_t x) { return (x + 255) & ~(size_t)255; }

extern "C" void kernel_launch(void* const* d_in, const int* in_sizes, int n_in,
                              void* d_out, int out_size, void* d_ws, size_t ws_size,
                              hipStream_t stream) {
    const float* x[4]  = {(const float*)d_in[0], (const float*)d_in[1],
                          (const float*)d_in[2], (const float*)d_in[3]};
    const int* ed[4]   = {(const int*)d_in[4], (const int*)d_in[5],
                          (const int*)d_in[6], (const int*)d_in[7]};
    const float* W1[4] = {(const float*)d_in[8],  (const float*)d_in[10],
                          (const float*)d_in[16], (const float*)d_in[18]};
    const float* b1[4] = {(const float*)d_in[9],  (const float*)d_in[11],
                          (const float*)d_in[17], (const float*)d_in[19]};
    const float* W2[4] = {(const float*)d_in[12], (const float*)d_in[14],
                          (const float*)d_in[20], (const float*)d_in[22]};
    const float* b2[4] = {(const float*)d_in[13], (const float*)d_in[15],
                          (const float*)d_in[21], (const float*)d_in[23]};
    const float* Wr[2] = {(const float*)d_in[24], (const float*)d_in[26]};
    const float* br[2] = {(const float*)d_in[25], (const float*)d_in[27]};

    float* out = (float*)d_out;
    const size_t S = (size_t)NN * 128;
    // out slots: 0 comb_l, 1 comb_p, 2 jl, 3 jp, 4 bl, 5 bp

    char* w = (char*)d_ws;
    int*   counts  = (int*)w;                w += alignup((size_t)4 * NN * 4);
    int*   rowptr  = (int*)w;                w += alignup((size_t)4 * (NN + 1) * 4);
    float* dinv    = (float*)w;              w += alignup((size_t)4 * NN * 4);
    int*   bsum    = (int*)w;                w += alignup((size_t)4 * 256 * 4);
    int*   bfill   = (int*)w;                w += alignup((size_t)4 * 128 * 4);
    int*   csr_src = (int*)w;                w += alignup((size_t)4 * NE * 4);
    unsigned short* xw1 = (unsigned short*)w;  w += alignup((size_t)NN * 256 * 2);
    unsigned short* hbf = (unsigned short*)w;  w += alignup((size_t)NN * 256 * 2);
    unsigned short* xw2 = (unsigned short*)w;  w += alignup((size_t)NN * 128 * 2);
    unsigned short* WtA = (unsigned short*)w;  w += alignup((size_t)(4 * 256 * 256 + 6 * 128 * 256) * 2);

    // pairbuf (4*NE*8B = 25.6MB) aliases xw1 (NN*256*2B = 25.6MB): pairbuf is
    // fully consumed by k_bucketB before the first k_gemm writes xw1 (stream-
    // ordered, disjoint live ranges).
    uint2* pairbuf = (uint2*)xw1;

    unsigned short* Wt1[4], * Wt2[4], * Wtr[2];
    {
        unsigned short* p = WtA;
        for (int i = 0; i < 4; i++) { Wt1[i] = p; p += 256 * 256; }
        for (int i = 0; i < 4; i++) { Wt2[i] = p; p += 128 * 256; }
        for (int i = 0; i < 2; i++) { Wtr[i] = p; p += 128 * 256; }
    }

    hipMemsetAsync(counts, 0, (size_t)4 * NN * 4, stream);

    dim3 egrid((NE + 255) / 256, 4);
    k_count<<<egrid, 256, 0, stream>>>(ed[0], ed[1], ed[2], ed[3], counts);
    k_deg<<<(4 * NN + 255) / 256, 256, 0, stream>>>(counts, dinv, 4 * NN);
    int nch = (NN + SCH - 1) / SCH;
    k_scan_a<<<dim3(nch, 4), SCH, 0, stream>>>(counts, bsum, NN);
    k_scan_b<<<dim3(1, 4), SCH, 0, stream>>>(bsum, nch);
    k_scan_c<<<dim3(nch, 4), SCH, 0, stream>>>(counts, bsum, rowptr, NN, nch);

    // bucketed CSR fill (line-coalesced writes; replaces random-scatter fill)
    k_binit<<<2, 256, 0, stream>>>(rowptr, bfill);
    k_bucketA<<<dim3((NE + ACH - 1) / ACH, 4), 256, 0, stream>>>(
            ed[0], ed[1], ed[2], ed[3], bfill, pairbuf);
    k_bucketB<<<dim3(NBUK, 4), 256, 0, stream>>>(pairbuf, rowptr, csr_src);

    {
        WTArgs a;
        for (int i = 0; i < 4; i++) { a.W[i] = W1[i];     a.Wt[i] = Wt1[i];     a.M[i] = 256; }
        for (int i = 0; i < 4; i++) { a.W[4 + i] = W2[i]; a.Wt[4 + i] = Wt2[i]; a.M[4 + i] = 128; }
        for (int i = 0; i < 2; i++) { a.W[8 + i] = Wr[i]; a.Wt[8 + i] = Wtr[i]; a.M[8 + i] = 128; }
        k_wT_all<<<dim3(256, 10), 256, 0, stream>>>(a);
    }

    const int gx = (NN + GB_BM - 1) / GB_BM;   // 391
    for (int p = 0; p < 4; p++) {
        const int* rp = rowptr + p * (NN + 1);
        const int* cs = csr_src + (size_t)p * NE;
        const float* dv = dinv + (size_t)p * NN;

        k_gemm<true><<<dim3(gx, 2), 256, 0, stream>>>(x[p], Wt1[p], NN, 256, 256,
                xw1, nullptr, nullptr, nullptr, nullptr, 0);
        k_aggregate<4><<<2048, 256, 0, stream>>>(xw1, rp, cs, dv, b1[p],
                hbf, nullptr, 0, NN);
        k_gemm<false><<<dim3(gx, 1), 256, 0, stream>>>(hbf, Wt2[p], NN, 256, 128,
                xw2, nullptr, nullptr, nullptr, nullptr, 0);
        k_aggregate<2><<<2048, 256, 0, stream>>>(xw2, rp, cs, dv, b2[p],
                nullptr, out + (2 + p) * S, 1, NN);
    }

    for (int t = 0; t < 2; t++) {
        const float* a0 = out + (2 + t) * S;   // jl / jp
        const float* a1 = out + (4 + t) * S;   // bl / bp
        k_gemm<true><<<dim3(gx, 1), 256, 0, stream>>>(x[t], Wtr[t], NN, 256, 128,
                nullptr, out + t * S, a0, a1, br[t], 1);
    }
}

// Round 3
// 1056.803 us; speedup vs baseline: 1.2831x; 1.1120x over previous
//
#include <hip/hip_runtime.h>
#include <cstddef>

#define NN 50000
#define NE 800000

typedef __bf16 bf16x8 __attribute__((ext_vector_type(8)));
typedef float floatx4 __attribute__((ext_vector_type(4)));

__device__ __forceinline__ float bflo2f(unsigned int u) {
    union { unsigned int u; float f; } v; v.u = u << 16; return v.f;
}
__device__ __forceinline__ float bfhi2f(unsigned int u) {
    union { unsigned int u; float f; } v; v.u = u & 0xffff0000u; return v.f;
}
__device__ __forceinline__ unsigned short f2bf(float f) {
    union { float f; unsigned int u; } v; v.f = f;
    unsigned int u = v.u;
    unsigned int r = u + 0x7fffu + ((u >> 16) & 1u);   // RNE
    return (unsigned short)(r >> 16);
}

// ---------------- bucketed CSR build ----------------
// No per-node global atomics anywhere. Buckets of 512 nodes; fixed-stride
// bucket segments in pairbuf (cap 12288 = mean 8192 + 45 sigma) remove the
// need for a pre-counting pass. Per-node counts/rowptr/dinv are computed in
// LDS inside pass B from each bucket's contiguous pair segment.

#define NBUK 98          // node >> 9  (512 nodes per bucket, 49999>>9 = 97)
#define BSH  9
#define ACH  4096        // edges per block in pass A
#define BKCAP 12288      // pairbuf capacity per bucket (also LDS CSR image cap)

// bfill[r*128+b] = b*BKCAP  (fixed-stride segment bases)
__global__ void k_binit2(int* __restrict__ bfill) {
    int i = blockIdx.x * blockDim.x + threadIdx.x;
    if (i < 4 * 128) bfill[i] = (i & 127) * BKCAP;
}

// Pass A: per-block LDS binning of a 4096-edge chunk, then per-bucket bulk
// reservation (one global atomic per block-bucket) and contiguous flush of
// (src,dst) pairs into the bucket's pair segment.
__global__ __launch_bounds__(256) void k_bucketA(
        const int* __restrict__ e0, const int* __restrict__ e1,
        const int* __restrict__ e2, const int* __restrict__ e3,
        int* __restrict__ bfill, uint2* __restrict__ pairbuf) {
    __shared__ int lcnt[128];
    __shared__ int s1[128];
    __shared__ int lbase[128];
    __shared__ int lfil[128];
    __shared__ int gbase[128];
    __shared__ uint2 sbuf[ACH];

    const int* es[4] = {e0, e1, e2, e3};
    const int r = blockIdx.y;
    const int tid = threadIdx.x;
    const int* src = es[r];
    const int* dst = es[r] + NE;
    const int lo = blockIdx.x * ACH;
    int hi = lo + ACH; if (hi > NE) hi = NE;
    const int cnt = hi - lo;

    if (tid < 128) lcnt[tid] = 0;
    __syncthreads();

    // histogram
    for (int i = lo + tid; i < hi; i += 256)
        atomicAdd(&lcnt[dst[i] >> BSH], 1);
    __syncthreads();

    // exclusive scan over 128 buckets (Hillis-Steele)
    if (tid < 128) s1[tid] = lcnt[tid];
    __syncthreads();
    for (int o = 1; o < 128; o <<= 1) {
        int x = (tid < 128 && tid >= o) ? s1[tid - o] : 0;
        __syncthreads();
        if (tid < 128) s1[tid] += x;
        __syncthreads();
    }
    if (tid < 128) {
        int eb = s1[tid] - lcnt[tid];
        lbase[tid] = eb;
        lfil[tid] = eb;
    }
    __syncthreads();

    // place pairs bucket-ordered in LDS
    for (int i = lo + tid; i < hi; i += 256) {
        int d = dst[i];
        int b = d >> BSH;
        int p = atomicAdd(&lfil[b], 1);
        uint2 v; v.x = (unsigned int)src[i]; v.y = (unsigned int)d;
        sbuf[p] = v;
    }
    __syncthreads();

    // reserve global space: one atomic per non-empty bucket
    if (tid < 128 && lcnt[tid] > 0)
        gbase[tid] = atomicAdd(&bfill[r * 128 + tid], lcnt[tid]);
    __syncthreads();

    // flush: contiguous runs per bucket (binary search slot -> bucket)
    uint2* pout = pairbuf + (size_t)r * (128 * (size_t)BKCAP);
    for (int i = tid; i < cnt; i += 256) {
        int loB = 0, hiB = 128;
        while (hiB - loB > 1) {
            int m = (loB + hiB) >> 1;
            if (lbase[m] <= i) loB = m; else hiB = m;
        }
        pout[(size_t)gbase[loB] + (i - lbase[loB])] = sbuf[i];
    }
}

// Tiny scan: bucket counts (from final bfill) -> per-relation exclusive scan
// = each bucket's global CSR segment base. Also caps rowptr.
__global__ void k_bscan(const int* __restrict__ bfill, int* __restrict__ bbase,
                        int* __restrict__ rowptr) {
    __shared__ int sd[128];
    int t = threadIdx.x;   // 128 threads
    for (int r = 0; r < 4; r++) {
        int c = bfill[r * 128 + t] - t * BKCAP;   // bucket count
        sd[t] = c; __syncthreads();
        for (int o = 1; o < 128; o <<= 1) {
            int x = (t >= o) ? sd[t - o] : 0; __syncthreads();
            sd[t] += x; __syncthreads();
        }
        bbase[r * 128 + t] = sd[t] - c;   // exclusive
        __syncthreads();
    }
    if (t == 0)
        for (int r = 0; r < 4; r++) rowptr[r * (NN + 1) + NN] = NE;
}

// Pass B: one block per bucket. Histogram per-node counts in LDS from the
// bucket's pair segment, scan 512 -> rowptr + dinv segments (coalesced),
// scatter src into LDS CSR image, write csr_src segment coalesced.
// Zero global atomics.
__global__ __launch_bounds__(256) void k_bucketB(
        const uint2* __restrict__ pairbuf, const int* __restrict__ bfill,
        const int* __restrict__ bbase, int* __restrict__ rowptr,
        float* __restrict__ dinv, int* __restrict__ csr_src) {
    __shared__ int csrimg[BKCAP];
    __shared__ int lcnt[512];
    __shared__ int lcur[512];

    const int r = blockIdx.y;
    const int b = blockIdx.x;
    const int tid = threadIdx.x;
    const int node_lo = b << BSH;
    int node_hi = node_lo + 512; if (node_hi > NN) node_hi = NN;
    const int nr = node_hi - node_lo;

    const int pbase = b * BKCAP;
    int cnt = bfill[r * 128 + b] - pbase;
    if (cnt > BKCAP) cnt = BKCAP;          // statistically unreachable guard
    const int seg0 = bbase[r * 128 + b];

    lcnt[tid] = 0; lcnt[tid + 256] = 0;
    __syncthreads();

    const uint2* pb = pairbuf + (size_t)r * (128 * (size_t)BKCAP) + pbase;
    // per-node histogram (pairs read is coalesced; re-read below hits L2)
    for (int i = tid; i < cnt; i += 256) {
        int li = (int)pb[i].y - node_lo;
        if (li >= 0 && li < 512) atomicAdd(&lcnt[li], 1);
    }
    __syncthreads();
    lcur[tid] = lcnt[tid]; lcur[tid + 256] = lcnt[tid + 256];
    __syncthreads();
    // inclusive scan over 512 (2 elems/thread; operands read pre-barrier)
    for (int o = 1; o < 512; o <<= 1) {
        int a0 = (tid >= o) ? lcnt[tid - o] : 0;
        int a1 = (tid + 256 >= o) ? lcnt[tid + 256 - o] : 0;
        __syncthreads();
        lcnt[tid] += a0; lcnt[tid + 256] += a1;
        __syncthreads();
    }
    // rowptr + dinv segments, init cursors
#pragma unroll
    for (int jj = 0; jj < 2; jj++) {
        int j = tid + jj * 256;
        int c = lcur[j];
        int excl = lcnt[j] - c;
        if (j < nr) {
            rowptr[r * (NN + 1) + node_lo + j] = seg0 + excl;
            dinv[r * NN + node_lo + j] = rsqrtf((float)(c + 1));
        }
        lcur[j] = excl;
    }
    __syncthreads();
    // scatter into LDS CSR image
    for (int i = tid; i < cnt; i += 256) {
        uint2 p = pb[i];
        int li = (int)p.y - node_lo;
        if (li >= 0 && li < 512) {
            int s = atomicAdd(&lcur[li], 1);
            if (s >= 0 && s < BKCAP) csrimg[s] = (int)p.x;
        }
    }
    __syncthreads();
    // coalesced CSR write
    int* co = csr_src + (size_t)r * NE + seg0;
    for (int k = tid; k < cnt; k += 256) co[k] = csrimg[k];
}

// ---------------- batched weight transpose: W[KxM] fp32 -> Wt[MxK] bf16 ----------------

struct WTArgs {
    const float* W[10];
    unsigned short* Wt[10];
    int M[10];   // K is always 256
};

__global__ void k_wT_all(WTArgs a) {
    int g = blockIdx.y;
    int M = a.M[g];
    int total = 256 * M;
    int i = blockIdx.x * blockDim.x + threadIdx.x;
    if (i < total) {
        int m = i >> 8, k = i & 255;        // i = m*256 + k (Wt layout [M x 256])
        a.Wt[g][i] = f2bf(a.W[g][(size_t)k * M + m]);
    }
}

// ---------------- MFMA GEMM ----------------
// C[nrows x ncols] = A[nrows x K] * Bt[ncols x K]^T
// AF32: A is fp32 (converted to bf16 while staging); else A is bf16.
// mode 0: store bf16 to outBf
// mode 1: outF = acc + bias[col] + 0.5*(add0+add1)   (fused residual combine)
#define GB_BM 128
#define GB_BN 128
#define GB_BK 32

template <bool AF32>
__global__ __launch_bounds__(256) void k_gemm(
        const void* __restrict__ Aptr, const unsigned short* __restrict__ Bt,
        int nrows, int K, int ncols,
        unsigned short* __restrict__ outBf, float* __restrict__ outF,
        const float* __restrict__ add0, const float* __restrict__ add1,
        const float* __restrict__ bias, int mode) {
    __shared__ __align__(16) unsigned short As[GB_BM][GB_BK];
    __shared__ __align__(16) unsigned short Bs[GB_BN][GB_BK];
    const int tid = threadIdx.x;
    const int lane = tid & 63;
    const int wid = tid >> 6;
    const int wm = (wid >> 1) * 64;
    const int wn = (wid & 1) * 64;
    const int row0 = blockIdx.x * GB_BM;
    const int col0 = blockIdx.y * GB_BN;
    const int lrow = lane & 15;
    const int lquad = lane >> 4;

    floatx4 acc[4][4];
#pragma unroll
    for (int i = 0; i < 4; i++)
#pragma unroll
        for (int j = 0; j < 4; j++) acc[i][j] = (floatx4){0.f, 0.f, 0.f, 0.f};

    for (int k0 = 0; k0 < K; k0 += GB_BK) {
#pragma unroll
        for (int t = 0; t < 2; t++) {
            int c = tid + t * 256;
            int r = c >> 2;
            int co = (c & 3) * 8;
            int gr = row0 + r; if (gr >= nrows) gr = nrows - 1;
            if constexpr (AF32) {
                const float* pa = (const float*)Aptr + (size_t)gr * K + k0 + co;
                float4 v0 = *(const float4*)pa;
                float4 v1 = *(const float4*)(pa + 4);
                uint4 o;
                o.x = (unsigned int)f2bf(v0.x) | ((unsigned int)f2bf(v0.y) << 16);
                o.y = (unsigned int)f2bf(v0.z) | ((unsigned int)f2bf(v0.w) << 16);
                o.z = (unsigned int)f2bf(v1.x) | ((unsigned int)f2bf(v1.y) << 16);
                o.w = (unsigned int)f2bf(v1.z) | ((unsigned int)f2bf(v1.w) << 16);
                *(uint4*)&As[r][co] = o;
            } else {
                *(uint4*)&As[r][co] =
                    *(const uint4*)((const unsigned short*)Aptr + (size_t)gr * K + k0 + co);
            }
            int gc = col0 + r;   // ncols multiple of 128 -> always valid
            *(uint4*)&Bs[r][co] = *(const uint4*)(Bt + (size_t)gc * K + k0 + co);
        }
        __syncthreads();
        bf16x8 af[4], bfr[4];
#pragma unroll
        for (int i = 0; i < 4; i++) af[i] = *(const bf16x8*)&As[wm + 16 * i + lrow][lquad * 8];
#pragma unroll
        for (int j = 0; j < 4; j++) bfr[j] = *(const bf16x8*)&Bs[wn + 16 * j + lrow][lquad * 8];
#pragma unroll
        for (int i = 0; i < 4; i++)
#pragma unroll
            for (int j = 0; j < 4; j++)
                acc[i][j] = __builtin_amdgcn_mfma_f32_16x16x32_bf16(af[i], bfr[j], acc[i][j], 0, 0, 0);
        __syncthreads();
    }

#pragma unroll
    for (int i = 0; i < 4; i++) {
#pragma unroll
        for (int j = 0; j < 4; j++) {
            int col = col0 + wn + 16 * j + lrow;
#pragma unroll
            for (int r = 0; r < 4; r++) {
                int row = row0 + wm + 16 * i + lquad * 4 + r;
                if (row < nrows) {
                    float v = acc[i][j][r];
                    size_t idx = (size_t)row * ncols + col;
                    if (mode == 0) {
                        outBf[idx] = f2bf(v);
                    } else {
                        outF[idx] = v + bias[col] + 0.5f * (add0[idx] + add1[idx]);
                    }
                }
            }
        }
    }
}

// ---------------- GCN aggregate (CSR gather) ----------------
// out = lrelu( di*( sum_e dinv[s]*xw[s] + di*xw[i] ) + bias ),  di = dinv[i]
// mode 0 -> bf16 outB ; mode 1 -> fp32 outF

__device__ __forceinline__ void ldrow4(const unsigned short* p, float* o) {
    uint2 r = *(const uint2*)p;
    o[0] = bflo2f(r.x & 0xffffu); o[1] = bfhi2f(r.x);
    o[2] = bflo2f(r.y & 0xffffu); o[3] = bfhi2f(r.y);
}
__device__ __forceinline__ void ldrow2(const unsigned short* p, float* o) {
    unsigned int r = *(const unsigned int*)p;
    o[0] = bflo2f(r & 0xffffu); o[1] = bfhi2f(r);
}

template <int NC>
__global__ __launch_bounds__(256) void k_aggregate(
        const unsigned short* __restrict__ xw,
        const int* __restrict__ rowptr,
        const int* __restrict__ cs,
        const float* __restrict__ dinv,
        const float* __restrict__ bias,
        unsigned short* __restrict__ outB,
        float* __restrict__ outF, int mode, int n) {
    constexpr int F = NC * 64;
    const int lane = threadIdx.x & 63;
    const int wid = blockIdx.x * (blockDim.x >> 6) + (threadIdx.x >> 6);
    const int nw = gridDim.x * (blockDim.x >> 6);
    const int fb = lane * NC;

    float bv[NC];
#pragma unroll
    for (int c = 0; c < NC; c++) bv[c] = bias[fb + c];

    for (int i = wid; i < n; i += nw) {
        float di = dinv[i];
        float acc[NC];
        {
            float rv[NC];
            if constexpr (NC == 4) ldrow4(xw + (size_t)i * F + fb, rv);
            else                   ldrow2(xw + (size_t)i * F + fb, rv);
#pragma unroll
            for (int c = 0; c < NC; c++) acc[c] = di * rv[c];
        }
        int e0 = rowptr[i], e1 = rowptr[i + 1];
        int j = e0;
        for (; j + 3 < e1; j += 4) {
            int s0 = cs[j], s1 = cs[j + 1], s2 = cs[j + 2], s3 = cs[j + 3];
            float c0 = dinv[s0], c1 = dinv[s1], c2 = dinv[s2], c3 = dinv[s3];
            float r0[NC], r1[NC], r2[NC], r3[NC];
            if constexpr (NC == 4) {
                ldrow4(xw + (size_t)s0 * F + fb, r0);
                ldrow4(xw + (size_t)s1 * F + fb, r1);
                ldrow4(xw + (size_t)s2 * F + fb, r2);
                ldrow4(xw + (size_t)s3 * F + fb, r3);
            } else {
                ldrow2(xw + (size_t)s0 * F + fb, r0);
                ldrow2(xw + (size_t)s1 * F + fb, r1);
                ldrow2(xw + (size_t)s2 * F + fb, r2);
                ldrow2(xw + (size_t)s3 * F + fb, r3);
            }
#pragma unroll
            for (int c = 0; c < NC; c++)
                acc[c] += c0 * r0[c] + c1 * r1[c] + c2 * r2[c] + c3 * r3[c];
        }
        for (; j < e1; j++) {
            int s = cs[j];
            float cf = dinv[s];
            float rv[NC];
            if constexpr (NC == 4) ldrow4(xw + (size_t)s * F + fb, rv);
            else                   ldrow2(xw + (size_t)s * F + fb, rv);
#pragma unroll
            for (int c = 0; c < NC; c++) acc[c] += cf * rv[c];
        }
#pragma unroll
        for (int c = 0; c < NC; c++) {
            float v = di * acc[c] + bv[c];
            acc[c] = v >= 0.f ? v : 0.2f * v;
        }
        if (mode == 0) {
            if constexpr (NC == 4) {
                uint2 o;
                o.x = (unsigned int)f2bf(acc[0]) | ((unsigned int)f2bf(acc[1]) << 16);
                o.y = (unsigned int)f2bf(acc[2]) | ((unsigned int)f2bf(acc[3]) << 16);
                *(uint2*)(outB + (size_t)i * F + fb) = o;
            } else {
                *(unsigned int*)(outB + (size_t)i * F + fb) =
                    (unsigned int)f2bf(acc[0]) | ((unsigned int)f2bf(acc[1]) << 16);
            }
        } else {
            if constexpr (NC == 4) {
                float4 o = {acc[0], acc[1], acc[2], acc[3]};
                *(float4*)(outF + (size_t)i * F + fb) = o;
            } else {
                float2 o = {acc[0], acc[1]};
                *(float2*)(outF + (size_t)i * F + fb) = o;
            }
        }
    }
}

// ---------------- host launch ----------------

static inline size_t alignup(size_t x) { return (x + 255) & ~(size_t)255; }

extern "C" void kernel_launch(void* const* d_in, const int* in_sizes, int n_in,
                              void* d_out, int out_size, void* d_ws, size_t ws_size,
                              hipStream_t stream) {
    const float* x[4]  = {(const float*)d_in[0], (const float*)d_in[1],
                          (const float*)d_in[2], (const float*)d_in[3]};
    const int* ed[4]   = {(const int*)d_in[4], (const int*)d_in[5],
                          (const int*)d_in[6], (const int*)d_in[7]};
    const float* W1[4] = {(const float*)d_in[8],  (const float*)d_in[10],
                          (const float*)d_in[16], (const float*)d_in[18]};
    const float* b1[4] = {(const float*)d_in[9],  (const float*)d_in[11],
                          (const float*)d_in[17], (const float*)d_in[19]};
    const float* W2[4] = {(const float*)d_in[12], (const float*)d_in[14],
                          (const float*)d_in[20], (const float*)d_in[22]};
    const float* b2[4] = {(const float*)d_in[13], (const float*)d_in[15],
                          (const float*)d_in[21], (const float*)d_in[23]};
    const float* Wr[2] = {(const float*)d_in[24], (const float*)d_in[26]};
    const float* br[2] = {(const float*)d_in[25], (const float*)d_in[27]};

    float* out = (float*)d_out;
    const size_t S = (size_t)NN * 128;
    // out slots: 0 comb_l, 1 comb_p, 2 jl, 3 jp, 4 bl, 5 bp

    char* w = (char*)d_ws;
    int*   rowptr  = (int*)w;                w += alignup((size_t)4 * (NN + 1) * 4);
    float* dinv    = (float*)w;              w += alignup((size_t)4 * NN * 4);
    int*   bfill   = (int*)w;                w += alignup((size_t)4 * 128 * 4);
    int*   bbase   = (int*)w;                w += alignup((size_t)4 * 128 * 4);
    int*   csr_src = (int*)w;                w += alignup((size_t)4 * NE * 4);
    unsigned short* xw1 = (unsigned short*)w;  w += alignup((size_t)NN * 256 * 2);
    unsigned short* hbf = (unsigned short*)w;  w += alignup((size_t)NN * 256 * 2);
    unsigned short* xw2 = (unsigned short*)w;  w += alignup((size_t)NN * 128 * 2);
    unsigned short* WtA = (unsigned short*)w;  w += alignup((size_t)(4 * 256 * 256 + 6 * 128 * 256) * 2);

    // pairbuf (4*128*12288*8B = 50.3MB) aliases xw1+hbf (25.6+25.6 = 51.2MB):
    // pairbuf is fully consumed by k_bucketB before the first k_gemm writes
    // xw1 (stream-ordered, disjoint live ranges).
    uint2* pairbuf = (uint2*)xw1;

    unsigned short* Wt1[4], * Wt2[4], * Wtr[2];
    {
        unsigned short* p = WtA;
        for (int i = 0; i < 4; i++) { Wt1[i] = p; p += 256 * 256; }
        for (int i = 0; i < 4; i++) { Wt2[i] = p; p += 128 * 256; }
        for (int i = 0; i < 2; i++) { Wtr[i] = p; p += 128 * 256; }
    }

    // bucketed CSR build (no per-node global atomics anywhere)
    k_binit2<<<2, 256, 0, stream>>>(bfill);
    k_bucketA<<<dim3((NE + ACH - 1) / ACH, 4), 256, 0, stream>>>(
            ed[0], ed[1], ed[2], ed[3], bfill, pairbuf);
    k_bscan<<<1, 128, 0, stream>>>(bfill, bbase, rowptr);
    k_bucketB<<<dim3(NBUK, 4), 256, 0, stream>>>(pairbuf, bfill, bbase,
            rowptr, dinv, csr_src);

    {
        WTArgs a;
        for (int i = 0; i < 4; i++) { a.W[i] = W1[i];     a.Wt[i] = Wt1[i];     a.M[i] = 256; }
        for (int i = 0; i < 4; i++) { a.W[4 + i] = W2[i]; a.Wt[4 + i] = Wt2[i]; a.M[4 + i] = 128; }
        for (int i = 0; i < 2; i++) { a.W[8 + i] = Wr[i]; a.Wt[8 + i] = Wtr[i]; a.M[8 + i] = 128; }
        k_wT_all<<<dim3(256, 10), 256, 0, stream>>>(a);
    }

    const int gx = (NN + GB_BM - 1) / GB_BM;   // 391
    for (int p = 0; p < 4; p++) {
        const int* rp = rowptr + p * (NN + 1);
        const int* cs = csr_src + (size_t)p * NE;
        const float* dv = dinv + (size_t)p * NN;

        k_gemm<true><<<dim3(gx, 2), 256, 0, stream>>>(x[p], Wt1[p], NN, 256, 256,
                xw1, nullptr, nullptr, nullptr, nullptr, 0);
        k_aggregate<4><<<2048, 256, 0, stream>>>(xw1, rp, cs, dv, b1[p],
                hbf, nullptr, 0, NN);
        k_gemm<false><<<dim3(gx, 1), 256, 0, stream>>>(hbf, Wt2[p], NN, 256, 128,
                xw2, nullptr, nullptr, nullptr, nullptr, 0);
        k_aggregate<2><<<2048, 256, 0, stream>>>(xw2, rp, cs, dv, b2[p],
                nullptr, out + (2 + p) * S, 1, NN);
    }

    for (int t = 0; t < 2; t++) {
        const float* a0 = out + (2 + t) * S;   // jl / jp
        const float* a1 = out + (4 + t) * S;   // bl / bp
        k_gemm<true><<<dim3(gx, 1), 256, 0, stream>>>(x[t], Wtr[t], NN, 256, 128,
                nullptr, out + t * S, a0, a1, br[t], 1);
    }
}

// Round 5
// 994.488 us; speedup vs baseline: 1.3635x; 1.0627x over previous
//
#include <hip/hip_runtime.h>
#include <cstddef>

#define NN 50000
#define NE 800000

typedef __bf16 bf16x8 __attribute__((ext_vector_type(8)));
typedef float floatx4 __attribute__((ext_vector_type(4)));

__device__ __forceinline__ float bflo2f(unsigned int u) {
    union { unsigned int u; float f; } v; v.u = u << 16; return v.f;
}
__device__ __forceinline__ float bfhi2f(unsigned int u) {
    union { unsigned int u; float f; } v; v.u = u & 0xffff0000u; return v.f;
}
__device__ __forceinline__ unsigned short f2bf(float f) {
    union { float f; unsigned int u; } v; v.f = f;
    unsigned int u = v.u;
    unsigned int r = u + 0x7fffu + ((u >> 16) & 1u);   // RNE
    return (unsigned short)(r >> 16);
}

// ---------------- bucketed CSR build ----------------
// No per-node global atomics anywhere. Buckets of 512 nodes; fixed-stride
// bucket segments in pairbuf (cap 12288 = mean 8192 + 45 sigma) remove the
// need for a pre-counting pass. Per-node counts/rowptr/dinv are computed in
// LDS inside pass B from each bucket's contiguous pair segment.

#define NBUK 98          // node >> 9  (512 nodes per bucket, 49999>>9 = 97)
#define BSH  9
#define ACH  4096        // edges per block in pass A
#define BKCAP 12288      // pairbuf capacity per bucket (also LDS CSR image cap)

// bfill[r*128+b] = b*BKCAP  (fixed-stride segment bases)
__global__ void k_binit2(int* __restrict__ bfill) {
    int i = blockIdx.x * blockDim.x + threadIdx.x;
    if (i < 4 * 128) bfill[i] = (i & 127) * BKCAP;
}

// Pass A: per-block LDS binning of a 4096-edge chunk, then per-bucket bulk
// reservation (one global atomic per block-bucket) and contiguous flush of
// (src,dst) pairs into the bucket's pair segment.
__global__ __launch_bounds__(256) void k_bucketA(
        const int* __restrict__ e0, const int* __restrict__ e1,
        const int* __restrict__ e2, const int* __restrict__ e3,
        int* __restrict__ bfill, uint2* __restrict__ pairbuf) {
    __shared__ int lcnt[128];
    __shared__ int s1[128];
    __shared__ int lbase[128];
    __shared__ int lfil[128];
    __shared__ int gbase[128];
    __shared__ uint2 sbuf[ACH];

    const int* es[4] = {e0, e1, e2, e3};
    const int r = blockIdx.y;
    const int tid = threadIdx.x;
    const int* src = es[r];
    const int* dst = es[r] + NE;
    const int lo = blockIdx.x * ACH;
    int hi = lo + ACH; if (hi > NE) hi = NE;
    const int cnt = hi - lo;

    if (tid < 128) lcnt[tid] = 0;
    __syncthreads();

    // histogram
    for (int i = lo + tid; i < hi; i += 256)
        atomicAdd(&lcnt[dst[i] >> BSH], 1);
    __syncthreads();

    // exclusive scan over 128 buckets (Hillis-Steele)
    if (tid < 128) s1[tid] = lcnt[tid];
    __syncthreads();
    for (int o = 1; o < 128; o <<= 1) {
        int x = (tid < 128 && tid >= o) ? s1[tid - o] : 0;
        __syncthreads();
        if (tid < 128) s1[tid] += x;
        __syncthreads();
    }
    if (tid < 128) {
        int eb = s1[tid] - lcnt[tid];
        lbase[tid] = eb;
        lfil[tid] = eb;
    }
    __syncthreads();

    // place pairs bucket-ordered in LDS
    for (int i = lo + tid; i < hi; i += 256) {
        int d = dst[i];
        int b = d >> BSH;
        int p = atomicAdd(&lfil[b], 1);
        uint2 v; v.x = (unsigned int)src[i]; v.y = (unsigned int)d;
        sbuf[p] = v;
    }
    __syncthreads();

    // reserve global space: one atomic per non-empty bucket
    if (tid < 128 && lcnt[tid] > 0)
        gbase[tid] = atomicAdd(&bfill[r * 128 + tid], lcnt[tid]);
    __syncthreads();

    // flush: contiguous runs per bucket (binary search slot -> bucket)
    uint2* pout = pairbuf + (size_t)r * (128 * (size_t)BKCAP);
    for (int i = tid; i < cnt; i += 256) {
        int loB = 0, hiB = 128;
        while (hiB - loB > 1) {
            int m = (loB + hiB) >> 1;
            if (lbase[m] <= i) loB = m; else hiB = m;
        }
        pout[(size_t)gbase[loB] + (i - lbase[loB])] = sbuf[i];
    }
}

// Tiny scan: bucket counts (from final bfill) -> per-relation exclusive scan
// = each bucket's global CSR segment base. Also caps rowptr.
__global__ void k_bscan(const int* __restrict__ bfill, int* __restrict__ bbase,
                        int* __restrict__ rowptr) {
    __shared__ int sd[128];
    int t = threadIdx.x;   // 128 threads
    for (int r = 0; r < 4; r++) {
        int c = bfill[r * 128 + t] - t * BKCAP;   // bucket count
        sd[t] = c; __syncthreads();
        for (int o = 1; o < 128; o <<= 1) {
            int x = (t >= o) ? sd[t - o] : 0; __syncthreads();
            sd[t] += x; __syncthreads();
        }
        bbase[r * 128 + t] = sd[t] - c;   // exclusive
        __syncthreads();
    }
    if (t == 0)
        for (int r = 0; r < 4; r++) rowptr[r * (NN + 1) + NN] = NE;
}

// Pass B: one block per bucket. Histogram per-node counts in LDS from the
// bucket's pair segment, scan 512 -> rowptr + dinv segments (coalesced),
// scatter src into LDS CSR image, write csr_src segment coalesced.
// Zero global atomics.
__global__ __launch_bounds__(256) void k_bucketB(
        const uint2* __restrict__ pairbuf, const int* __restrict__ bfill,
        const int* __restrict__ bbase, int* __restrict__ rowptr,
        float* __restrict__ dinv, int* __restrict__ csr_src) {
    __shared__ int csrimg[BKCAP];
    __shared__ int lcnt[512];
    __shared__ int lcur[512];

    const int r = blockIdx.y;
    const int b = blockIdx.x;
    const int tid = threadIdx.x;
    const int node_lo = b << BSH;
    int node_hi = node_lo + 512; if (node_hi > NN) node_hi = NN;
    const int nr = node_hi - node_lo;

    const int pbase = b * BKCAP;
    int cnt = bfill[r * 128 + b] - pbase;
    if (cnt > BKCAP) cnt = BKCAP;          // statistically unreachable guard
    const int seg0 = bbase[r * 128 + b];

    lcnt[tid] = 0; lcnt[tid + 256] = 0;
    __syncthreads();

    const uint2* pb = pairbuf + (size_t)r * (128 * (size_t)BKCAP) + pbase;
    // per-node histogram (pairs read is coalesced; re-read below hits L2)
    for (int i = tid; i < cnt; i += 256) {
        int li = (int)pb[i].y - node_lo;
        if (li >= 0 && li < 512) atomicAdd(&lcnt[li], 1);
    }
    __syncthreads();
    lcur[tid] = lcnt[tid]; lcur[tid + 256] = lcnt[tid + 256];
    __syncthreads();
    // inclusive scan over 512 (2 elems/thread; operands read pre-barrier)
    for (int o = 1; o < 512; o <<= 1) {
        int a0 = (tid >= o) ? lcnt[tid - o] : 0;
        int a1 = (tid + 256 >= o) ? lcnt[tid + 256 - o] : 0;
        __syncthreads();
        lcnt[tid] += a0; lcnt[tid + 256] += a1;
        __syncthreads();
    }
    // rowptr + dinv segments, init cursors
#pragma unroll
    for (int jj = 0; jj < 2; jj++) {
        int j = tid + jj * 256;
        int c = lcur[j];
        int excl = lcnt[j] - c;
        if (j < nr) {
            rowptr[r * (NN + 1) + node_lo + j] = seg0 + excl;
            dinv[r * NN + node_lo + j] = rsqrtf((float)(c + 1));
        }
        lcur[j] = excl;
    }
    __syncthreads();
    // scatter into LDS CSR image
    for (int i = tid; i < cnt; i += 256) {
        uint2 p = pb[i];
        int li = (int)p.y - node_lo;
        if (li >= 0 && li < 512) {
            int s = atomicAdd(&lcur[li], 1);
            if (s >= 0 && s < BKCAP) csrimg[s] = (int)p.x;
        }
    }
    __syncthreads();
    // coalesced CSR write
    int* co = csr_src + (size_t)r * NE + seg0;
    for (int k = tid; k < cnt; k += 256) co[k] = csrimg[k];
}

// ---------------- batched weight transpose: W[KxM] fp32 -> Wt[MxK] bf16 ----------------

struct WTArgs {
    const float* W[10];
    unsigned short* Wt[10];
    int M[10];   // K is always 256
};

__global__ void k_wT_all(WTArgs a) {
    int g = blockIdx.y;
    int M = a.M[g];
    int total = 256 * M;
    int i = blockIdx.x * blockDim.x + threadIdx.x;
    if (i < total) {
        int m = i >> 8, k = i & 255;        // i = m*256 + k (Wt layout [M x 256])
        a.Wt[g][i] = f2bf(a.W[g][(size_t)k * M + m]);
    }
}

// ---------------- MFMA GEMM (batched over blockIdx.z) ----------------
// Per z: C[nrows x ncols] = A[z][nrows x K] * Bt[z][ncols x K]^T
// AF32: A is fp32 (converted to bf16 while staging); else A is bf16.
// mode 0: store bf16 to outBf[z]
// mode 1: outF[z] = acc + bias[z][col] + 0.5*(add0[z]+add1[z])
#define GB_BM 128
#define GB_BN 128
#define GB_BK 32

struct GemmArgs {
    const void* A[4];
    const unsigned short* Bt[4];
    unsigned short* outBf[4];
    float* outF[4];
    const float* add0[4];
    const float* add1[4];
    const float* bias[4];
};

template <bool AF32>
__global__ __launch_bounds__(256) void k_gemmB(
        GemmArgs g, int nrows, int K, int ncols, int mode) {
    __shared__ __align__(16) unsigned short As[GB_BM][GB_BK];
    __shared__ __align__(16) unsigned short Bs[GB_BN][GB_BK];
    const int z = blockIdx.z;
    const void* __restrict__ Aptr = g.A[z];
    const unsigned short* __restrict__ Bt = g.Bt[z];
    const int tid = threadIdx.x;
    const int lane = tid & 63;
    const int wid = tid >> 6;
    const int wm = (wid >> 1) * 64;
    const int wn = (wid & 1) * 64;
    const int row0 = blockIdx.x * GB_BM;
    const int col0 = blockIdx.y * GB_BN;
    const int lrow = lane & 15;
    const int lquad = lane >> 4;

    floatx4 acc[4][4];
#pragma unroll
    for (int i = 0; i < 4; i++)
#pragma unroll
        for (int j = 0; j < 4; j++) acc[i][j] = (floatx4){0.f, 0.f, 0.f, 0.f};

    for (int k0 = 0; k0 < K; k0 += GB_BK) {
#pragma unroll
        for (int t = 0; t < 2; t++) {
            int c = tid + t * 256;
            int r = c >> 2;
            int co = (c & 3) * 8;
            int gr = row0 + r; if (gr >= nrows) gr = nrows - 1;
            if constexpr (AF32) {
                const float* pa = (const float*)Aptr + (size_t)gr * K + k0 + co;
                float4 v0 = *(const float4*)pa;
                float4 v1 = *(const float4*)(pa + 4);
                uint4 o;
                o.x = (unsigned int)f2bf(v0.x) | ((unsigned int)f2bf(v0.y) << 16);
                o.y = (unsigned int)f2bf(v0.z) | ((unsigned int)f2bf(v0.w) << 16);
                o.z = (unsigned int)f2bf(v1.x) | ((unsigned int)f2bf(v1.y) << 16);
                o.w = (unsigned int)f2bf(v1.z) | ((unsigned int)f2bf(v1.w) << 16);
                *(uint4*)&As[r][co] = o;
            } else {
                *(uint4*)&As[r][co] =
                    *(const uint4*)((const unsigned short*)Aptr + (size_t)gr * K + k0 + co);
            }
            int gc = col0 + r;   // ncols multiple of 128 -> always valid
            *(uint4*)&Bs[r][co] = *(const uint4*)(Bt + (size_t)gc * K + k0 + co);
        }
        __syncthreads();
        bf16x8 af[4], bfr[4];
#pragma unroll
        for (int i = 0; i < 4; i++) af[i] = *(const bf16x8*)&As[wm + 16 * i + lrow][lquad * 8];
#pragma unroll
        for (int j = 0; j < 4; j++) bfr[j] = *(const bf16x8*)&Bs[wn + 16 * j + lrow][lquad * 8];
#pragma unroll
        for (int i = 0; i < 4; i++)
#pragma unroll
            for (int j = 0; j < 4; j++)
                acc[i][j] = __builtin_amdgcn_mfma_f32_16x16x32_bf16(af[i], bfr[j], acc[i][j], 0, 0, 0);
        __syncthreads();
    }

    unsigned short* outBf = g.outBf[z];
    float* outF = g.outF[z];
    const float* add0 = g.add0[z];
    const float* add1 = g.add1[z];
    const float* bias = g.bias[z];
#pragma unroll
    for (int i = 0; i < 4; i++) {
#pragma unroll
        for (int j = 0; j < 4; j++) {
            int col = col0 + wn + 16 * j + lrow;
#pragma unroll
            for (int r = 0; r < 4; r++) {
                int row = row0 + wm + 16 * i + lquad * 4 + r;
                if (row < nrows) {
                    float v = acc[i][j][r];
                    size_t idx = (size_t)row * ncols + col;
                    if (mode == 0) {
                        outBf[idx] = f2bf(v);
                    } else {
                        outF[idx] = v + bias[col] + 0.5f * (add0[idx] + add1[idx]);
                    }
                }
            }
        }
    }
}

// ---------------- GCN aggregate (CSR gather, batched over blockIdx.y) ----------------
// out = lrelu( di*( sum_e dinv[s]*xw[s] + di*xw[i] ) + bias ),  di = dinv[i]
// mode 0 -> bf16 outB ; mode 1 -> fp32 outF

__device__ __forceinline__ void ldrow4(const unsigned short* p, float* o) {
    uint2 r = *(const uint2*)p;
    o[0] = bflo2f(r.x & 0xffffu); o[1] = bfhi2f(r.x);
    o[2] = bflo2f(r.y & 0xffffu); o[3] = bfhi2f(r.y);
}
__device__ __forceinline__ void ldrow2(const unsigned short* p, float* o) {
    unsigned int r = *(const unsigned int*)p;
    o[0] = bflo2f(r & 0xffffu); o[1] = bfhi2f(r);
}

struct AggArgs {
    const unsigned short* xw[4];
    const int* rp[4];
    const int* cs[4];
    const float* dv[4];
    const float* bias[4];
    unsigned short* outB[4];
    float* outF[4];
};

template <int NC>
__global__ __launch_bounds__(256) void k_aggB(AggArgs a, int mode, int n) {
    constexpr int F = NC * 64;
    const int rel = blockIdx.y;
    const unsigned short* __restrict__ xw = a.xw[rel];
    const int* __restrict__ rowptr = a.rp[rel];
    const int* __restrict__ cs = a.cs[rel];
    const float* __restrict__ dinv = a.dv[rel];
    const float* __restrict__ bias = a.bias[rel];
    unsigned short* __restrict__ outB = a.outB[rel];
    float* __restrict__ outF = a.outF[rel];

    const int lane = threadIdx.x & 63;
    const int wid = blockIdx.x * (blockDim.x >> 6) + (threadIdx.x >> 6);
    const int nw = gridDim.x * (blockDim.x >> 6);
    const int fb = lane * NC;

    float bv[NC];
#pragma unroll
    for (int c = 0; c < NC; c++) bv[c] = bias[fb + c];

    for (int i = wid; i < n; i += nw) {
        float di = dinv[i];
        float acc[NC];
        {
            float rv[NC];
            if constexpr (NC == 4) ldrow4(xw + (size_t)i * F + fb, rv);
            else                   ldrow2(xw + (size_t)i * F + fb, rv);
#pragma unroll
            for (int c = 0; c < NC; c++) acc[c] = di * rv[c];
        }
        int e0 = rowptr[i], e1 = rowptr[i + 1];
        int j = e0;
        for (; j + 3 < e1; j += 4) {
            int s0 = cs[j], s1 = cs[j + 1], s2 = cs[j + 2], s3 = cs[j + 3];
            float c0 = dinv[s0], c1 = dinv[s1], c2 = dinv[s2], c3 = dinv[s3];
            float r0[NC], r1[NC], r2[NC], r3[NC];
            if constexpr (NC == 4) {
                ldrow4(xw + (size_t)s0 * F + fb, r0);
                ldrow4(xw + (size_t)s1 * F + fb, r1);
                ldrow4(xw + (size_t)s2 * F + fb, r2);
                ldrow4(xw + (size_t)s3 * F + fb, r3);
            } else {
                ldrow2(xw + (size_t)s0 * F + fb, r0);
                ldrow2(xw + (size_t)s1 * F + fb, r1);
                ldrow2(xw + (size_t)s2 * F + fb, r2);
                ldrow2(xw + (size_t)s3 * F + fb, r3);
            }
#pragma unroll
            for (int c = 0; c < NC; c++)
                acc[c] += c0 * r0[c] + c1 * r1[c] + c2 * r2[c] + c3 * r3[c];
        }
        for (; j < e1; j++) {
            int s = cs[j];
            float cf = dinv[s];
            float rv[NC];
            if constexpr (NC == 4) ldrow4(xw + (size_t)s * F + fb, rv);
            else                   ldrow2(xw + (size_t)s * F + fb, rv);
#pragma unroll
            for (int c = 0; c < NC; c++) acc[c] += cf * rv[c];
        }
#pragma unroll
        for (int c = 0; c < NC; c++) {
            float v = di * acc[c] + bv[c];
            acc[c] = v >= 0.f ? v : 0.2f * v;
        }
        if (mode == 0) {
            if constexpr (NC == 4) {
                uint2 o;
                o.x = (unsigned int)f2bf(acc[0]) | ((unsigned int)f2bf(acc[1]) << 16);
                o.y = (unsigned int)f2bf(acc[2]) | ((unsigned int)f2bf(acc[3]) << 16);
                *(uint2*)(outB + (size_t)i * F + fb) = o;
            } else {
                *(unsigned int*)(outB + (size_t)i * F + fb) =
                    (unsigned int)f2bf(acc[0]) | ((unsigned int)f2bf(acc[1]) << 16);
            }
        } else {
            if constexpr (NC == 4) {
                float4 o = {acc[0], acc[1], acc[2], acc[3]};
                *(float4*)(outF + (size_t)i * F + fb) = o;
            } else {
                float2 o = {acc[0], acc[1]};
                *(float2*)(outF + (size_t)i * F + fb) = o;
            }
        }
    }
}

// ---------------- host launch ----------------

static inline size_t alignup(size_t x) { return (x + 255) & ~(size_t)255; }

extern "C" void kernel_launch(void* const* d_in, const int* in_sizes, int n_in,
                              void* d_out, int out_size, void* d_ws, size_t ws_size,
                              hipStream_t stream) {
    const float* x[4]  = {(const float*)d_in[0], (const float*)d_in[1],
                          (const float*)d_in[2], (const float*)d_in[3]};
    const int* ed[4]   = {(const int*)d_in[4], (const int*)d_in[5],
                          (const int*)d_in[6], (const int*)d_in[7]};
    const float* W1[4] = {(const float*)d_in[8],  (const float*)d_in[10],
                          (const float*)d_in[16], (const float*)d_in[18]};
    const float* b1[4] = {(const float*)d_in[9],  (const float*)d_in[11],
                          (const float*)d_in[17], (const float*)d_in[19]};
    const float* W2[4] = {(const float*)d_in[12], (const float*)d_in[14],
                          (const float*)d_in[20], (const float*)d_in[22]};
    const float* b2[4] = {(const float*)d_in[13], (const float*)d_in[15],
                          (const float*)d_in[21], (const float*)d_in[23]};
    const float* Wr[2] = {(const float*)d_in[24], (const float*)d_in[26]};
    const float* br[2] = {(const float*)d_in[25], (const float*)d_in[27]};

    float* out = (float*)d_out;
    const size_t S = (size_t)NN * 128;
    // out slots: 0 comb_l, 1 comb_p, 2 jl, 3 jp, 4 bl, 5 bp

    char* w = (char*)d_ws;
    int*   rowptr  = (int*)w;                w += alignup((size_t)4 * (NN + 1) * 4);
    float* dinv    = (float*)w;              w += alignup((size_t)4 * NN * 4);
    int*   bfill   = (int*)w;                w += alignup((size_t)4 * 128 * 4);
    int*   bbase   = (int*)w;                w += alignup((size_t)4 * 128 * 4);
    int*   csr_src = (int*)w;                w += alignup((size_t)4 * NE * 4);
    unsigned short* WtA = (unsigned short*)w;  w += alignup((size_t)(4 * 256 * 256 + 6 * 128 * 256) * 2);
    // per-relation intermediates (enables cross-relation batching)
    unsigned short* xw1 = (unsigned short*)w;  w += alignup((size_t)4 * NN * 256 * 2);   // 102.4 MB
    unsigned short* hbf = (unsigned short*)w;  w += alignup((size_t)4 * NN * 256 * 2);   // 102.4 MB
    unsigned short* xw2 = (unsigned short*)w;  w += alignup((size_t)4 * NN * 128 * 2);   //  51.2 MB

    // pairbuf (4*128*12288*8B = 50.3MB) aliases the xw1 block (102.4MB):
    // pairbuf is fully consumed by k_bucketB before K1 writes xw1
    // (stream-ordered, disjoint live ranges).
    uint2* pairbuf = (uint2*)xw1;

    unsigned short* Wt1[4], * Wt2[4], * Wtr[2];
    {
        unsigned short* p = WtA;
        for (int i = 0; i < 4; i++) { Wt1[i] = p; p += 256 * 256; }
        for (int i = 0; i < 4; i++) { Wt2[i] = p; p += 128 * 256; }
        for (int i = 0; i < 2; i++) { Wtr[i] = p; p += 128 * 256; }
    }
    unsigned short* xw1r[4], * hbfr[4], * xw2r[4];
    for (int i = 0; i < 4; i++) {
        xw1r[i] = xw1 + (size_t)i * NN * 256;
        hbfr[i] = hbf + (size_t)i * NN * 256;
        xw2r[i] = xw2 + (size_t)i * NN * 128;
    }

    // bucketed CSR build (no per-node global atomics anywhere)
    k_binit2<<<2, 256, 0, stream>>>(bfill);
    k_bucketA<<<dim3((NE + ACH - 1) / ACH, 4), 256, 0, stream>>>(
            ed[0], ed[1], ed[2], ed[3], bfill, pairbuf);
    k_bscan<<<1, 128, 0, stream>>>(bfill, bbase, rowptr);
    k_bucketB<<<dim3(NBUK, 4), 256, 0, stream>>>(pairbuf, bfill, bbase,
            rowptr, dinv, csr_src);

    {
        WTArgs a;
        for (int i = 0; i < 4; i++) { a.W[i] = W1[i];     a.Wt[i] = Wt1[i];     a.M[i] = 256; }
        for (int i = 0; i < 4; i++) { a.W[4 + i] = W2[i]; a.Wt[4 + i] = Wt2[i]; a.M[4 + i] = 128; }
        for (int i = 0; i < 2; i++) { a.W[8 + i] = Wr[i]; a.Wt[8 + i] = Wtr[i]; a.M[8 + i] = 128; }
        k_wT_all<<<dim3(256, 10), 256, 0, stream>>>(a);
    }

    const int gx = (NN + GB_BM - 1) / GB_BM;   // 391

    // K1: layer-1 GEMM, all 4 relations
    {
        GemmArgs g{};
        for (int p = 0; p < 4; p++) {
            g.A[p] = x[p]; g.Bt[p] = Wt1[p]; g.outBf[p] = xw1r[p];
            g.outF[p] = nullptr; g.add0[p] = nullptr; g.add1[p] = nullptr; g.bias[p] = nullptr;
        }
        k_gemmB<true><<<dim3(gx, 2, 4), 256, 0, stream>>>(g, NN, 256, 256, 0);
    }
    // K2: layer-1 aggregate, all 4 relations
    {
        AggArgs a{};
        for (int p = 0; p < 4; p++) {
            a.xw[p] = xw1r[p]; a.rp[p] = rowptr + p * (NN + 1);
            a.cs[p] = csr_src + (size_t)p * NE; a.dv[p] = dinv + (size_t)p * NN;
            a.bias[p] = b1[p]; a.outB[p] = hbfr[p]; a.outF[p] = nullptr;
        }
        k_aggB<4><<<dim3(2048, 4), 256, 0, stream>>>(a, 0, NN);
    }
    // K3: layer-2 GEMM, all 4 relations
    {
        GemmArgs g{};
        for (int p = 0; p < 4; p++) {
            g.A[p] = hbfr[p]; g.Bt[p] = Wt2[p]; g.outBf[p] = xw2r[p];
            g.outF[p] = nullptr; g.add0[p] = nullptr; g.add1[p] = nullptr; g.bias[p] = nullptr;
        }
        k_gemmB<false><<<dim3(gx, 1, 4), 256, 0, stream>>>(g, NN, 256, 128, 0);
    }
    // K4: layer-2 aggregate, all 4 relations -> jl/jp/bl/bp
    {
        AggArgs a{};
        for (int p = 0; p < 4; p++) {
            a.xw[p] = xw2r[p]; a.rp[p] = rowptr + p * (NN + 1);
            a.cs[p] = csr_src + (size_t)p * NE; a.dv[p] = dinv + (size_t)p * NN;
            a.bias[p] = b2[p]; a.outB[p] = nullptr; a.outF[p] = out + (2 + p) * S;
        }
        k_aggB<2><<<dim3(2048, 4), 256, 0, stream>>>(a, 1, NN);
    }
    // K5: residual GEMM + view combine, both node types
    {
        GemmArgs g{};
        for (int t = 0; t < 2; t++) {
            g.A[t] = x[t]; g.Bt[t] = Wtr[t]; g.outBf[t] = nullptr;
            g.outF[t] = out + t * S;
            g.add0[t] = out + (2 + t) * S;   // jl / jp
            g.add1[t] = out + (4 + t) * S;   // bl / bp
            g.bias[t] = br[t];
        }
        k_gemmB<true><<<dim3(gx, 1, 2), 256, 0, stream>>>(g, NN, 256, 128, 1);
    }
}